// Round 24
// baseline (106.762 us; speedup 1.0000x reference)
//
#include <hip/hip_runtime.h>
#include <hip/hip_bf16.h>

typedef unsigned short ushort_t;
typedef short bf16x8 __attribute__((ext_vector_type(8)));
typedef float f32x4 __attribute__((ext_vector_type(4)));

__device__ __forceinline__ ushort_t f2b(float f) {
    __hip_bfloat16 h = __float2bfloat16(f);
    return *reinterpret_cast<ushort_t*>(&h);
}
__device__ __forceinline__ float b2f(short v) {
    union { unsigned int u; float f; } cv;
    cv.u = ((unsigned int)(ushort_t)v) << 16;
    return cv.f;
}

// ---------------- all weight repacks in one kernel (693 blocks)
// w1 k-order (conv1): k<24: ky=k>>3, q=k&7, kx=q/3, c=q%3 ; k=24..26: (ky=k-24, kx=2, c=2); k>=27: 0
__global__ __launch_bounds__(256) void k_packall(const float* __restrict__ w1,
                                                 const float* __restrict__ w2,
                                                 const float* __restrict__ w3,
                                                 const float* __restrict__ w4,
                                                 ushort_t* __restrict__ o1,
                                                 ushort_t* __restrict__ o2,
                                                 ushort_t* __restrict__ o3,
                                                 ushort_t* __restrict__ o4m) {
    const int bx = blockIdx.x;
    if (bx < 512) {
        const int co = bx;
        __shared__ float sw[2304];
        for (int i = threadIdx.x; i < 2304; i += 256) sw[i] = w4[(size_t)co * 2304 + i];
        __syncthreads();
        const int g = co >> 4, l15 = co & 15;
        for (int it = threadIdx.x; it < 288; it += 256) {
            const int kc = it >> 2, kg = it & 3;
            const int k0 = kc * 32 + kg * 8;
            const int tap = k0 >> 8, ci0 = k0 & 255;
            const int lane = kg * 16 + l15;
            ushort_t tmp[8];
#pragma unroll
            for (int j = 0; j < 8; ++j)
                tmp[j] = f2b(sw[(ci0 + j) * 9 + tap]);
            *(float4*)(o4m + ((size_t)(kc * 32 + g) * 64 + lane) * 8) = *(const float4*)tmp;
        }
    } else if (bx < 656) {
        const int slot = (bx - 512) * 256 + threadIdx.x;
        const int lane = slot & 63, g = (slot >> 6) & 15, kc = slot >> 10;
        const int k0 = kc * 32 + ((lane >> 4) << 3);
        const int tap = k0 >> 7, cib = k0 & 127;
        const int ky = tap >= 6 ? 2 : (tap >= 3 ? 1 : 0), kx = tap - ky * 3;
        const int co = g * 16 + (lane & 15);
#pragma unroll
        for (int j = 0; j < 8; ++j)
            o3[slot * 8 + j] = f2b(w3[((co * 128 + cib + j) * 3 + ky) * 3 + kx]);
    } else if (bx < 692) {
        const int slot = (bx - 656) * 256 + threadIdx.x;
        const int lane = slot & 63, g = (slot >> 6) & 7, kc = slot >> 9;
        const int k0 = kc * 32 + ((lane >> 4) << 3);
        const int tap = k0 >> 6, sb = k0 & 63;
        const int ky = tap >= 6 ? 2 : (tap >= 3 ? 1 : 0), kx = tap - ky * 3;
        const int co = g * 16 + (lane & 15);
#pragma unroll
        for (int j = 0; j < 8; ++j) {
            const int s = sb + j;
            const int ci = 16 * (s & 3) + (s >> 2);
            o2[slot * 8 + j] = f2b(w2[((co * 64 + ci) * 3 + ky) * 3 + kx]);
        }
    } else {
        const int slot = threadIdx.x;
        const int lane = slot & 63, nf = slot >> 6;
        const int co = nf * 16 + (lane & 15);
        const int kg = lane >> 4;
#pragma unroll
        for (int j = 0; j < 8; ++j) {
            const int k = kg * 8 + j;
            float v = 0.f;
            if (k < 24) {
                const int ky = k >> 3, q = k & 7;
                const int kx = q / 3, c = q - 3 * kx;
                v = w1[(co * 3 + c) * 9 + ky * 3 + kx];
            } else if (k < 27) {
                const int ky = k - 24;
                v = w1[(co * 3 + 2) * 9 + ky * 3 + 2];
            }
            o1[slot * 8 + j] = f2b(v);
        }
    }
}

// ---------------- fused conv1 (x-split, contiguous-gather LDS layout, float4 staging)
__global__ __launch_bounds__(256) void k_conv1f(const float* __restrict__ x,
                                                const ushort_t* __restrict__ wpk1,
                                                const float* __restrict__ b1,
                                                ushort_t* __restrict__ y1) {
    const int rp = blockIdx.x, xh = blockIdx.y, b = blockIdx.z;
    const int tid = threadIdx.x;
    const int wid = tid >> 6, lane = tid & 63;
    const int l15 = lane & 15, kg = lane >> 4;

    __shared__ __align__(16) ushort_t sX[9 * 776];        // 13968 B
    const float* xb = x + (size_t)b * 3 * 512 * 512;
    const int iy0 = 8 * rp - 1;
#pragma unroll
    for (int pass = 0; pass < 7; ++pass) {
        const int cr = pass * 4 + wid;                    // 0..27
        if (cr < 27) {
            const int c = cr / 9, r = cr - 9 * (cr / 9);
            const int iy = iy0 + r;
            float4 q = {0.f, 0.f, 0.f, 0.f};
            if (iy >= 0)
                q = *(const float4*)(xb + ((size_t)c * 512 + iy) * 512 + 256 * xh + 4 * lane);
            const int base = r * 776 + (4 * lane + 1) * 3 + c;
            sX[base]     = f2b(q.x);
            sX[base + 3] = f2b(q.y);
            sX[base + 6] = f2b(q.z);
            sX[base + 9] = f2b(q.w);
        }
    }
    if (tid < 27) {                                       // colx = 0 (x col 256*xh-1)
        const int c = tid / 9, r = tid - 9 * (tid / 9);
        const int iy = iy0 + r;
        const int ix = 256 * xh - 1;
        float v = (iy >= 0 && ix >= 0) ? xb[((size_t)c * 512 + iy) * 512 + ix] : 0.f;
        sX[r * 776 + c] = f2b(v);
    }
    __syncthreads();

    const int gq = l15 >> 2;
    const int dy = (l15 >> 1) & 1, dx = l15 & 1;

    bf16x8 bF[4];
    float bias[4];
#pragma unroll
    for (int nf = 0; nf < 4; ++nf) {
        bF[nf] = *reinterpret_cast<const bf16x8*>(wpk1 + (size_t)(nf * 64 + lane) * 8);
        bias[nf] = b1[nf * 16 + l15];
    }
    const f32x4 z4 = {0.f, 0.f, 0.f, 0.f};

#pragma unroll 4
    for (int it = 0; it < 8; ++it) {
        const int fl = wid * 8 + it;
        const int g2 = fl * 4 + gq;
        const int pyl = g2 >> 6, pxl = g2 & 63;
        const int cr = 2 * pyl + dy;
        const int oxl = 2 * pxl + dx;
        bf16x8 aF;
        if (kg < 3) {
            const int ba = (2 * cr + kg) * 776 + 6 * oxl; // even -> 4B-aligned bytes
            const unsigned int* pu = (const unsigned int*)(sX + ba);
            union { unsigned int u[4]; bf16x8 v; } cvt;
            cvt.u[0] = pu[0]; cvt.u[1] = pu[1]; cvt.u[2] = pu[2]; cvt.u[3] = pu[3];
            aF = cvt.v;
        } else {
            const int b0 = 2 * cr * 776 + 6 * oxl + 8;
            aF = (bf16x8){0, 0, 0, 0, 0, 0, 0, 0};
            aF[0] = (short)sX[b0];
            aF[1] = (short)sX[b0 + 776];
            aF[2] = (short)sX[b0 + 1552];
        }
        f32x4 acc[4];
#pragma unroll
        for (int nf = 0; nf < 4; ++nf)
            acc[nf] = __builtin_amdgcn_mfma_f32_16x16x32_bf16(aF, bF[nf], z4, 0, 0, 0);
        const int g_out = fl * 4 + kg;
        const int pyo = g_out >> 6, pxo = xh * 64 + (g_out & 63);
        union { ushort_t u[4]; uint2 v; } pk;
#pragma unroll
        for (int nf = 0; nf < 4; ++nf) {
            float v = fmaxf(fmaxf(acc[nf][0], acc[nf][1]), fmaxf(acc[nf][2], acc[nf][3]));
            pk.u[nf] = f2b(fmaxf(v + bias[nf], 0.f));
        }
        *(uint2*)(y1 + ((size_t)(b * 128 + 2 * rp + pyo) * 128 + pxo) * 64 + 4 * l15) = pk.v;
    }
}

// ---------------- conv2 LDS-staged MFMA (x-quarter split: 24.5KB LDS, 6 blocks/CU)
__global__ __launch_bounds__(256) void k_conv2s(const ushort_t* __restrict__ y1,
                                                const ushort_t* __restrict__ wpk2,
                                                const float* __restrict__ b2,
                                                ushort_t* __restrict__ y2) {
    const int b = blockIdx.z;
    const int xq = blockIdx.y;
    const int rp = blockIdx.x;
    const int tid = threadIdx.x;
    const int wid = tid >> 6, lane = tid & 63;
    const int l15 = lane & 15, kg = lane >> 4;

    __shared__ __align__(16) ushort_t sY[170 * 72];       // 24480 B
    bf16x8* sYv = (bf16x8*)sY;

    const ushort_t* xb = y1 + (size_t)b * 128 * 128 * 64;
    const int iyb = 4 * rp - 1, ixb = 32 * xq - 1;
    for (int j = tid; j < 1360; j += 256) {               // 170 px x 8 chunks
        const int q = j & 7;
        const int pc = j >> 3;
        const int cc = pc % 34, r = pc / 34;
        const int iy = iyb + r, ix = ixb + cc;
        bf16x8 v = {0, 0, 0, 0, 0, 0, 0, 0};
        if (iy >= 0 && ix >= 0 && ix < 128)
            v = *reinterpret_cast<const bf16x8*>(xb + ((size_t)iy * 128 + ix) * 64 + q * 8);
        sYv[pc * 9 + (q ^ ((pc >> 1) & 7))] = v;
    }
    __syncthreads();

    const f32x4 z4 = {0.f, 0.f, 0.f, 0.f};
    f32x4 acc[2][2];                          // [oyi][nf]
#pragma unroll
    for (int i = 0; i < 2; ++i) { acc[i][0] = z4; acc[i][1] = z4; }

#pragma unroll 1
    for (int tap = 0; tap < 9; ++tap) {
        const int ky = tap >= 6 ? 2 : (tap >= 3 ? 1 : 0), kx = tap - ky * 3;
#pragma unroll
        for (int h = 0; h < 2; ++h) {
            const int kc = tap * 2 + h;
            const int c8 = h * 4 + kg;
            bf16x8 aF[2];
#pragma unroll
            for (int oyi = 0; oyi < 2; ++oyi) {
                const int pc = (2 * oyi + ky) * 34 + 2 * l15 + kx;
                aF[oyi] = sYv[pc * 9 + (c8 ^ ((pc >> 1) & 7))];
            }
            bf16x8 bF[2];
#pragma unroll
            for (int nf = 0; nf < 2; ++nf)
                bF[nf] = *reinterpret_cast<const bf16x8*>(wpk2 + ((size_t)(kc * 8 + wid * 2 + nf) * 64 + lane) * 8);
#pragma unroll
            for (int oyi = 0; oyi < 2; ++oyi)
#pragma unroll
            for (int nf = 0; nf < 2; ++nf)
                acc[oyi][nf] = __builtin_amdgcn_mfma_f32_16x16x32_bf16(aF[oyi], bF[nf], acc[oyi][nf], 0, 0, 0);
        }
    }
#pragma unroll
    for (int nf = 0; nf < 2; ++nf) {
        const int co = wid * 32 + nf * 16 + l15;
        const float bias = b2[co];
#pragma unroll
        for (int p = 0; p < 2; ++p) {
            float v = fmaxf(fmaxf(acc[0][nf][2 * p], acc[0][nf][2 * p + 1]),
                            fmaxf(acc[1][nf][2 * p], acc[1][nf][2 * p + 1]));
            const int px = xq * 8 + kg * 2 + p;
            y2[((size_t)(b * 32 + rp) * 32 + px) * 128 + co] = f2b(fmaxf(v + bias, 0.f));
        }
    }
}

// ---------------- conv3 MFMA (gy-split: 512 blocks, 2 conv rows / 1 pooled row per wave)
__global__ __launch_bounds__(256) void k_conv3m(const ushort_t* __restrict__ y2,
                                                const ushort_t* __restrict__ wpk3,
                                                const float* __restrict__ b3,
                                                ushort_t* __restrict__ y3) {
    const int gy = blockIdx.x, gn = blockIdx.y, b = blockIdx.z;   // gy = pooled row 0..7
    const int oy0 = gy * 2;                                       // conv rows oy0, oy0+1
    const int tid = threadIdx.x;
    const int wid = tid >> 6, lane = tid & 63;
    const int l15 = lane & 15, kl8 = (lane >> 4) << 3;
    const int g16 = gn * 4 + wid;
    const int co = g16 * 16 + l15;

    const ushort_t* xb = y2 + (size_t)b * 32 * 32 * 128;
    const f32x4 z4 = {0.f, 0.f, 0.f, 0.f};
    f32x4 acc[2] = {z4, z4};

#pragma unroll 1
    for (int tap = 0; tap < 9; ++tap) {
        const int ky = tap >= 6 ? 2 : (tap >= 3 ? 1 : 0), kx = tap - ky * 3;
        const int iyA = 2 * oy0 - 1 + ky;
        const int c = 2 * l15 - 1 + kx;
        const bool cok = (c >= 0);
#pragma unroll
        for (int h = 0; h < 4; ++h) {
            const int ci0 = h * 32;
            const int kc = tap * 4 + h;
            bf16x8 aF[2];
#pragma unroll
            for (int mf = 0; mf < 2; ++mf) {
                const int iy = iyA + 2 * mf;
                bf16x8 r = {0, 0, 0, 0, 0, 0, 0, 0};
                if (cok && iy >= 0) r = *reinterpret_cast<const bf16x8*>(xb + ((size_t)iy * 32 + c) * 128 + ci0 + kl8);
                aF[mf] = r;
            }
            const bf16x8 bF = *reinterpret_cast<const bf16x8*>(wpk3 + ((size_t)(kc * 16 + g16) * 64 + lane) * 8);
#pragma unroll
            for (int mf = 0; mf < 2; ++mf)
                acc[mf] = __builtin_amdgcn_mfma_f32_16x16x32_bf16(aF[mf], bF, acc[mf], 0, 0, 0);
        }
    }
    const int kg = lane >> 4;
    const float bias = b3[co];
#pragma unroll
    for (int p = 0; p < 2; ++p) {
        float v = fmaxf(fmaxf(acc[0][2 * p], acc[0][2 * p + 1]),
                        fmaxf(acc[1][2 * p], acc[1][2 * p + 1]));
        const int px = kg * 2 + p;
        y3[((size_t)(b * 8 + gy) * 8 + px) * 256 + co] = f2b(fmaxf(v + bias, 0.f));
    }
}

// ---------------- conv4 GEMM + relu + mean, fused im2col gather from y3 (K-split 4 waves)
__global__ __launch_bounds__(256) void k_conv4g(const ushort_t* __restrict__ y3,
                                                const ushort_t* __restrict__ wpk4m,
                                                const float* __restrict__ b4,
                                                float* __restrict__ feats) {
    const int g16 = blockIdx.x, b = blockIdx.y;
    const int tid = threadIdx.x, wid = tid >> 6, lane = tid & 63;
    const int l15 = lane & 15, kg = lane >> 4, kl8 = kg << 3;
    const int oy = l15 >> 2, ox = l15 & 3;
    const f32x4 z4 = {0.f, 0.f, 0.f, 0.f};
    f32x4 acc = z4;
    const ushort_t* yb = y3 + (size_t)b * 16384;
    const int kc0 = wid * 18;

#pragma unroll 3
    for (int i = 0; i < 18; ++i) {
        const int kc = kc0 + i;
        const int k0 = kc * 32 + kl8;
        const int tap = k0 >> 8, ci0 = k0 & 255;
        const int ky = tap / 3, kx = tap - 3 * (tap / 3);
        const int iy = 2 * oy - 1 + ky, ix = 2 * ox - 1 + kx;
        bf16x8 aF = {0, 0, 0, 0, 0, 0, 0, 0};
        if (iy >= 0 && ix >= 0)
            aF = *reinterpret_cast<const bf16x8*>(yb + ((iy * 8 + ix) << 8) + ci0);
        const bf16x8 bF = *reinterpret_cast<const bf16x8*>(wpk4m + ((size_t)(kc * 32 + g16) * 64 + lane) * 8);
        acc = __builtin_amdgcn_mfma_f32_16x16x32_bf16(aF, bF, acc, 0, 0, 0);
    }

    __shared__ f32x4 red[4][64];
    red[wid][lane] = acc;
    __syncthreads();
    if (wid == 0) {
        f32x4 t = red[0][lane];
        t = t + red[1][lane];
        t = t + red[2][lane];
        t = t + red[3][lane];
        const int co = g16 * 16 + l15;
        const float bias = b4[co];
        float s = fmaxf(t[0] + bias, 0.f) + fmaxf(t[1] + bias, 0.f)
                + fmaxf(t[2] + bias, 0.f) + fmaxf(t[3] + bias, 0.f);
        s += __shfl_xor(s, 16, 64);
        s += __shfl_xor(s, 32, 64);
        if (kg == 0) feats[b * 512 + co] = s * 0.0625f;
    }
}

// ---------------- head (parallel logits + split writes, bf16 vlad): grid (b=16, slice=8)
__global__ __launch_bounds__(256) void k_head(const float* __restrict__ feats,
                                              const float* __restrict__ wv,
                                              const float* __restrict__ bv,
                                              const float* __restrict__ centroids,
                                              ushort_t* __restrict__ v) {
    const int b = blockIdx.x, sl8 = blockIdx.y;
    __shared__ float sf[512];
    __shared__ float plog[4][64];
    __shared__ float sl[64];
    __shared__ float sa[64];
    for (int i = threadIdx.x; i < 512; i += 256) sf[i] = feats[b * 512 + i];
    __syncthreads();
    {
        const int k = threadIdx.x & 63, q = threadIdx.x >> 6;   // c-quarter
        float s = 0.f;
        const int c0 = q * 128;
        for (int c = c0; c < c0 + 128; ++c) s += sf[c] * wv[(size_t)k * 512 + c];
        plog[q][k] = s;
    }
    __syncthreads();
    if (threadIdx.x < 64) {
        const int k = threadIdx.x;
        sl[k] = plog[0][k] + plog[1][k] + plog[2][k] + plog[3][k] + bv[k];
    }
    __syncthreads();
    if (threadIdx.x < 64) {
        const int k = threadIdx.x;
        float m = -1e30f;
        for (int i = 0; i < 64; ++i) m = fmaxf(m, sl[i]);
        float sum = 0.f;
        for (int i = 0; i < 64; ++i) sum += __expf(sl[i] - m);
        sa[k] = __expf(sl[k] - m) / sum;
    }
    __syncthreads();
    const int i4end = (sl8 + 1) * 4096;
    for (int i4 = sl8 * 4096 + threadIdx.x * 4; i4 < i4end; i4 += 1024) {
        const int k = i4 >> 9;
        const float a_ = sa[k];
        const float4 c4 = *(const float4*)(centroids + i4);
        const float4 f4 = *(const float4*)(&sf[i4 & 511]);
        union { ushort_t u[4]; uint2 w; } pk;
        pk.u[0] = f2b(a_ * (f4.x - c4.x));
        pk.u[1] = f2b(a_ * (f4.y - c4.y));
        pk.u[2] = f2b(a_ * (f4.z - c4.z));
        pk.u[3] = f2b(a_ * (f4.w - c4.w));
        *(uint2*)(v + (size_t)b * 32768 + i4) = pk.w;
    }
}

// ---------------- fc1 MFMA (barrier-free): part = v_bf16[16 x 32768] @ fw1^T
// grid (g16=16, by=64); wave (by,wid) owns kc = by*16+wid*4..+4, writes part[ks=by*4+wid]
__global__ __launch_bounds__(256) void k_fc1m(const ushort_t* __restrict__ v,
                                              const float* __restrict__ fw1,
                                              float* __restrict__ part) {
    const int g16 = blockIdx.x, by = blockIdx.y;
    const int tid = threadIdx.x, wid = tid >> 6, lane = tid & 63;
    const int l15 = lane & 15, kg = lane >> 4;
    const f32x4 z4 = {0.f, 0.f, 0.f, 0.f};
    f32x4 acc = z4;
    const ushort_t* vrow = v + (size_t)l15 * 32768;                // batch = l15
    const float* wrow = fw1 + (size_t)(g16 * 16 + l15) * 32768;    // d = g16*16+l15
    const int kc0 = by * 16 + wid * 4;

#pragma unroll
    for (int i = 0; i < 4; ++i) {
        const int j0 = (kc0 + i) * 32 + kg * 8;
        const bf16x8 aF = *reinterpret_cast<const bf16x8*>(vrow + j0);
        const float4 wa = *(const float4*)(wrow + j0);
        const float4 wb = *(const float4*)(wrow + j0 + 4);
        bf16x8 bF;
        bF[0] = (short)f2b(wa.x); bF[1] = (short)f2b(wa.y);
        bF[2] = (short)f2b(wa.z); bF[3] = (short)f2b(wa.w);
        bF[4] = (short)f2b(wb.x); bF[5] = (short)f2b(wb.y);
        bF[6] = (short)f2b(wb.z); bF[7] = (short)f2b(wb.w);
        acc = __builtin_amdgcn_mfma_f32_16x16x32_bf16(aF, bF, acc, 0, 0, 0);
    }

    // direct per-wave partial write: ks = by*4+wid; C row = kg*4+r (batch), col = l15 (d)
    const int ks = by * 4 + wid;
#pragma unroll
    for (int r = 0; r < 4; ++r)
        part[((size_t)ks * 16 + (kg * 4 + r)) * 256 + g16 * 16 + l15] = acc[r];
}

// ---------------- fc2 (+fc1 reduce/bias/relu) + L2 norm; 256 K-partials, 1024 threads
__global__ __launch_bounds__(1024) void k_fc2(const float* __restrict__ part,
                                              const float* __restrict__ fb1,
                                              const float* __restrict__ fw2,
                                              const float* __restrict__ fb2,
                                              float* __restrict__ out) {
    const int b = blockIdx.x;
    const int tid = threadIdx.x;
    const int dd = tid & 255, jq = tid >> 8;              // 4 quarters
    __shared__ float sd[256];
    __shared__ float pr[4][256];
    __shared__ float sq[256];
    // fc1 reduce: 256 ks split across jq (64 each)
    float t = 0.f;
    const int ks0 = jq * 64;
    for (int ks = ks0; ks < ks0 + 64; ++ks) t += part[((size_t)ks * 16 + b) * 256 + dd];
    pr[jq][dd] = t;
    __syncthreads();
    if (jq == 0)
        sd[dd] = fmaxf(pr[0][dd] + pr[1][dd] + pr[2][dd] + pr[3][dd] + fb1[dd], 0.f);
    __syncthreads();
    // fc2: j-range split across jq
    float s = 0.f;
    const int j0 = jq * 64;
    for (int j = j0; j < j0 + 64; ++j) s += sd[j] * fw2[(size_t)dd * 256 + j];
    pr[jq][dd] = s;
    __syncthreads();
    float sfull = 0.f;
    if (jq == 0) {
        sfull = pr[0][dd] + pr[1][dd] + pr[2][dd] + pr[3][dd] + fb2[dd];
        sq[dd] = sfull * sfull;
    }
    __syncthreads();
    for (int off = 128; off >= 1; off >>= 1) {
        if (jq == 0 && dd < off) sq[dd] += sq[dd + off];
        __syncthreads();
    }
    if (jq == 0) out[b * 256 + dd] = sfull * rsqrtf(sq[0]);
}

extern "C" void kernel_launch(void* const* d_in, const int* in_sizes, int n_in,
                              void* d_out, int out_size, void* d_ws, size_t ws_size,
                              hipStream_t stream) {
    const float* x    = (const float*)d_in[0];
    const float* w1   = (const float*)d_in[1];
    const float* b1   = (const float*)d_in[2];
    const float* w2   = (const float*)d_in[3];
    const float* b2   = (const float*)d_in[4];
    const float* w3   = (const float*)d_in[5];
    const float* b3   = (const float*)d_in[6];
    const float* w4   = (const float*)d_in[7];
    const float* b4   = (const float*)d_in[8];
    const float* wv   = (const float*)d_in[9];
    const float* bv   = (const float*)d_in[10];
    const float* cen  = (const float*)d_in[11];
    const float* fw1  = (const float*)d_in[12];
    const float* fb1  = (const float*)d_in[13];
    const float* fw2  = (const float*)d_in[14];
    const float* fb2  = (const float*)d_in[15];
    float* out = (float*)d_out;

    char* p = (char*)d_ws;
    ushort_t* y1    = (ushort_t*)p; p += 33554432;  // 16*128*128*64 bf16
    ushort_t* wpk2  = (ushort_t*)p; p += 147456;    // 73728 bf16
    ushort_t* wpk3  = (ushort_t*)p; p += 589824;    // 294912 bf16
    ushort_t* wpk4m = (ushort_t*)p; p += 2359296;   // 1179648 bf16
    ushort_t* wpk1  = (ushort_t*)p; p += 4096;      // 2048 bf16
    ushort_t* y2    = (ushort_t*)p; p += 4194304;   // 16*32*32*128 bf16
    ushort_t* y3    = (ushort_t*)p; p += 524288;    // 16*8*8*256 bf16
    float*    feats = (float*)p;    p += 32768;     // 16*512
    ushort_t* vbuf  = (ushort_t*)p; p += 1048576;   // 16*32768 bf16
    float*    part  = (float*)p;    p += 4194304;   // 256*16*256 f32

    k_packall<<<693, 256, 0, stream>>>(w1, w2, w3, w4, wpk1, wpk2, wpk3, wpk4m);
    k_conv1f<<<dim3(64, 2, 16), 256, 0, stream>>>(x, wpk1, b1, y1);
    k_conv2s<<<dim3(32, 4, 16), 256, 0, stream>>>(y1, wpk2, b2, y2);
    k_conv3m<<<dim3(8, 4, 16), 256, 0, stream>>>(y2, wpk3, b3, y3);
    k_conv4g<<<dim3(32, 16), 256, 0, stream>>>(y3, wpk4m, b4, feats);
    k_head<<<dim3(16, 8), 256, 0, stream>>>(feats, wv, bv, cen, vbuf);
    k_fc1m<<<dim3(16, 64), 256, 0, stream>>>(vbuf, fw1, part);
    k_fc2<<<16, 1024, 0, stream>>>(part, fb1, fw2, fb2, out);
}

// Round 25
// 103.971 us; speedup vs baseline: 1.0268x; 1.0268x over previous
//
#include <hip/hip_runtime.h>
#include <hip/hip_bf16.h>

typedef unsigned short ushort_t;
typedef short bf16x8 __attribute__((ext_vector_type(8)));
typedef float f32x4 __attribute__((ext_vector_type(4)));

__device__ __forceinline__ ushort_t f2b(float f) {
    __hip_bfloat16 h = __float2bfloat16(f);
    return *reinterpret_cast<ushort_t*>(&h);
}
__device__ __forceinline__ float b2f(short v) {
    union { unsigned int u; float f; } cv;
    cv.u = ((unsigned int)(ushort_t)v) << 16;
    return cv.f;
}

// ---------------- all weight repacks in one kernel (693 blocks)
// w1 k-order (conv1): k<24: ky=k>>3, q=k&7, kx=q/3, c=q%3 ; k=24..26: (ky=k-24, kx=2, c=2); k>=27: 0
__global__ __launch_bounds__(256) void k_packall(const float* __restrict__ w1,
                                                 const float* __restrict__ w2,
                                                 const float* __restrict__ w3,
                                                 const float* __restrict__ w4,
                                                 ushort_t* __restrict__ o1,
                                                 ushort_t* __restrict__ o2,
                                                 ushort_t* __restrict__ o3,
                                                 ushort_t* __restrict__ o4m) {
    const int bx = blockIdx.x;
    if (bx < 512) {
        const int co = bx;
        __shared__ float sw[2304];
        for (int i = threadIdx.x; i < 2304; i += 256) sw[i] = w4[(size_t)co * 2304 + i];
        __syncthreads();
        const int g = co >> 4, l15 = co & 15;
        for (int it = threadIdx.x; it < 288; it += 256) {
            const int kc = it >> 2, kg = it & 3;
            const int k0 = kc * 32 + kg * 8;
            const int tap = k0 >> 8, ci0 = k0 & 255;
            const int lane = kg * 16 + l15;
            ushort_t tmp[8];
#pragma unroll
            for (int j = 0; j < 8; ++j)
                tmp[j] = f2b(sw[(ci0 + j) * 9 + tap]);
            *(float4*)(o4m + ((size_t)(kc * 32 + g) * 64 + lane) * 8) = *(const float4*)tmp;
        }
    } else if (bx < 656) {
        const int slot = (bx - 512) * 256 + threadIdx.x;
        const int lane = slot & 63, g = (slot >> 6) & 15, kc = slot >> 10;
        const int k0 = kc * 32 + ((lane >> 4) << 3);
        const int tap = k0 >> 7, cib = k0 & 127;
        const int ky = tap >= 6 ? 2 : (tap >= 3 ? 1 : 0), kx = tap - ky * 3;
        const int co = g * 16 + (lane & 15);
#pragma unroll
        for (int j = 0; j < 8; ++j)
            o3[slot * 8 + j] = f2b(w3[((co * 128 + cib + j) * 3 + ky) * 3 + kx]);
    } else if (bx < 692) {
        const int slot = (bx - 656) * 256 + threadIdx.x;
        const int lane = slot & 63, g = (slot >> 6) & 7, kc = slot >> 9;
        const int k0 = kc * 32 + ((lane >> 4) << 3);
        const int tap = k0 >> 6, sb = k0 & 63;
        const int ky = tap >= 6 ? 2 : (tap >= 3 ? 1 : 0), kx = tap - ky * 3;
        const int co = g * 16 + (lane & 15);
#pragma unroll
        for (int j = 0; j < 8; ++j) {
            const int s = sb + j;
            const int ci = 16 * (s & 3) + (s >> 2);
            o2[slot * 8 + j] = f2b(w2[((co * 64 + ci) * 3 + ky) * 3 + kx]);
        }
    } else {
        const int slot = threadIdx.x;
        const int lane = slot & 63, nf = slot >> 6;
        const int co = nf * 16 + (lane & 15);
        const int kg = lane >> 4;
#pragma unroll
        for (int j = 0; j < 8; ++j) {
            const int k = kg * 8 + j;
            float v = 0.f;
            if (k < 24) {
                const int ky = k >> 3, q = k & 7;
                const int kx = q / 3, c = q - 3 * kx;
                v = w1[(co * 3 + c) * 9 + ky * 3 + kx];
            } else if (k < 27) {
                const int ky = k - 24;
                v = w1[(co * 3 + 2) * 9 + ky * 3 + 2];
            }
            o1[slot * 8 + j] = f2b(v);
        }
    }
}

// ---------------- fused conv1 (x-split, contiguous-gather LDS layout, float4 staging)
__global__ __launch_bounds__(256) void k_conv1f(const float* __restrict__ x,
                                                const ushort_t* __restrict__ wpk1,
                                                const float* __restrict__ b1,
                                                ushort_t* __restrict__ y1) {
    const int rp = blockIdx.x, xh = blockIdx.y, b = blockIdx.z;
    const int tid = threadIdx.x;
    const int wid = tid >> 6, lane = tid & 63;
    const int l15 = lane & 15, kg = lane >> 4;

    __shared__ __align__(16) ushort_t sX[9 * 776];        // 13968 B
    const float* xb = x + (size_t)b * 3 * 512 * 512;
    const int iy0 = 8 * rp - 1;
#pragma unroll
    for (int pass = 0; pass < 7; ++pass) {
        const int cr = pass * 4 + wid;                    // 0..27
        if (cr < 27) {
            const int c = cr / 9, r = cr - 9 * (cr / 9);
            const int iy = iy0 + r;
            float4 q = {0.f, 0.f, 0.f, 0.f};
            if (iy >= 0)
                q = *(const float4*)(xb + ((size_t)c * 512 + iy) * 512 + 256 * xh + 4 * lane);
            const int base = r * 776 + (4 * lane + 1) * 3 + c;
            sX[base]     = f2b(q.x);
            sX[base + 3] = f2b(q.y);
            sX[base + 6] = f2b(q.z);
            sX[base + 9] = f2b(q.w);
        }
    }
    if (tid < 27) {                                       // colx = 0 (x col 256*xh-1)
        const int c = tid / 9, r = tid - 9 * (tid / 9);
        const int iy = iy0 + r;
        const int ix = 256 * xh - 1;
        float v = (iy >= 0 && ix >= 0) ? xb[((size_t)c * 512 + iy) * 512 + ix] : 0.f;
        sX[r * 776 + c] = f2b(v);
    }
    __syncthreads();

    const int gq = l15 >> 2;
    const int dy = (l15 >> 1) & 1, dx = l15 & 1;

    bf16x8 bF[4];
    float bias[4];
#pragma unroll
    for (int nf = 0; nf < 4; ++nf) {
        bF[nf] = *reinterpret_cast<const bf16x8*>(wpk1 + (size_t)(nf * 64 + lane) * 8);
        bias[nf] = b1[nf * 16 + l15];
    }
    const f32x4 z4 = {0.f, 0.f, 0.f, 0.f};

#pragma unroll 4
    for (int it = 0; it < 8; ++it) {
        const int fl = wid * 8 + it;
        const int g2 = fl * 4 + gq;
        const int pyl = g2 >> 6, pxl = g2 & 63;
        const int cr = 2 * pyl + dy;
        const int oxl = 2 * pxl + dx;
        bf16x8 aF;
        if (kg < 3) {
            const int ba = (2 * cr + kg) * 776 + 6 * oxl; // even -> 4B-aligned bytes
            const unsigned int* pu = (const unsigned int*)(sX + ba);
            union { unsigned int u[4]; bf16x8 v; } cvt;
            cvt.u[0] = pu[0]; cvt.u[1] = pu[1]; cvt.u[2] = pu[2]; cvt.u[3] = pu[3];
            aF = cvt.v;
        } else {
            const int b0 = 2 * cr * 776 + 6 * oxl + 8;
            aF = (bf16x8){0, 0, 0, 0, 0, 0, 0, 0};
            aF[0] = (short)sX[b0];
            aF[1] = (short)sX[b0 + 776];
            aF[2] = (short)sX[b0 + 1552];
        }
        f32x4 acc[4];
#pragma unroll
        for (int nf = 0; nf < 4; ++nf)
            acc[nf] = __builtin_amdgcn_mfma_f32_16x16x32_bf16(aF, bF[nf], z4, 0, 0, 0);
        const int g_out = fl * 4 + kg;
        const int pyo = g_out >> 6, pxo = xh * 64 + (g_out & 63);
        union { ushort_t u[4]; uint2 v; } pk;
#pragma unroll
        for (int nf = 0; nf < 4; ++nf) {
            float v = fmaxf(fmaxf(acc[nf][0], acc[nf][1]), fmaxf(acc[nf][2], acc[nf][3]));
            pk.u[nf] = f2b(fmaxf(v + bias[nf], 0.f));
        }
        *(uint2*)(y1 + ((size_t)(b * 128 + 2 * rp + pyo) * 128 + pxo) * 64 + 4 * l15) = pk.v;
    }
}

// ---------------- conv2 LDS-staged MFMA (x-quarter split: 24.5KB LDS, 6 blocks/CU)
__global__ __launch_bounds__(256) void k_conv2s(const ushort_t* __restrict__ y1,
                                                const ushort_t* __restrict__ wpk2,
                                                const float* __restrict__ b2,
                                                ushort_t* __restrict__ y2) {
    const int b = blockIdx.z;
    const int xq = blockIdx.y;
    const int rp = blockIdx.x;
    const int tid = threadIdx.x;
    const int wid = tid >> 6, lane = tid & 63;
    const int l15 = lane & 15, kg = lane >> 4;

    __shared__ __align__(16) ushort_t sY[170 * 72];       // 24480 B
    bf16x8* sYv = (bf16x8*)sY;

    const ushort_t* xb = y1 + (size_t)b * 128 * 128 * 64;
    const int iyb = 4 * rp - 1, ixb = 32 * xq - 1;
    for (int j = tid; j < 1360; j += 256) {               // 170 px x 8 chunks
        const int q = j & 7;
        const int pc = j >> 3;
        const int cc = pc % 34, r = pc / 34;
        const int iy = iyb + r, ix = ixb + cc;
        bf16x8 v = {0, 0, 0, 0, 0, 0, 0, 0};
        if (iy >= 0 && ix >= 0 && ix < 128)
            v = *reinterpret_cast<const bf16x8*>(xb + ((size_t)iy * 128 + ix) * 64 + q * 8);
        sYv[pc * 9 + (q ^ ((pc >> 1) & 7))] = v;
    }
    __syncthreads();

    const f32x4 z4 = {0.f, 0.f, 0.f, 0.f};
    f32x4 acc[2][2];                          // [oyi][nf]
#pragma unroll
    for (int i = 0; i < 2; ++i) { acc[i][0] = z4; acc[i][1] = z4; }

#pragma unroll 1
    for (int tap = 0; tap < 9; ++tap) {
        const int ky = tap >= 6 ? 2 : (tap >= 3 ? 1 : 0), kx = tap - ky * 3;
#pragma unroll
        for (int h = 0; h < 2; ++h) {
            const int kc = tap * 2 + h;
            const int c8 = h * 4 + kg;
            bf16x8 aF[2];
#pragma unroll
            for (int oyi = 0; oyi < 2; ++oyi) {
                const int pc = (2 * oyi + ky) * 34 + 2 * l15 + kx;
                aF[oyi] = sYv[pc * 9 + (c8 ^ ((pc >> 1) & 7))];
            }
            bf16x8 bF[2];
#pragma unroll
            for (int nf = 0; nf < 2; ++nf)
                bF[nf] = *reinterpret_cast<const bf16x8*>(wpk2 + ((size_t)(kc * 8 + wid * 2 + nf) * 64 + lane) * 8);
#pragma unroll
            for (int oyi = 0; oyi < 2; ++oyi)
#pragma unroll
            for (int nf = 0; nf < 2; ++nf)
                acc[oyi][nf] = __builtin_amdgcn_mfma_f32_16x16x32_bf16(aF[oyi], bF[nf], acc[oyi][nf], 0, 0, 0);
        }
    }
#pragma unroll
    for (int nf = 0; nf < 2; ++nf) {
        const int co = wid * 32 + nf * 16 + l15;
        const float bias = b2[co];
#pragma unroll
        for (int p = 0; p < 2; ++p) {
            float v = fmaxf(fmaxf(acc[0][nf][2 * p], acc[0][nf][2 * p + 1]),
                            fmaxf(acc[1][nf][2 * p], acc[1][nf][2 * p + 1]));
            const int px = xq * 8 + kg * 2 + p;
            y2[((size_t)(b * 32 + rp) * 32 + px) * 128 + co] = f2b(fmaxf(v + bias, 0.f));
        }
    }
}

// ---------------- conv3 MFMA (gy-split: 512 blocks, 2 conv rows / 1 pooled row per wave)
__global__ __launch_bounds__(256) void k_conv3m(const ushort_t* __restrict__ y2,
                                                const ushort_t* __restrict__ wpk3,
                                                const float* __restrict__ b3,
                                                ushort_t* __restrict__ y3) {
    const int gy = blockIdx.x, gn = blockIdx.y, b = blockIdx.z;   // gy = pooled row 0..7
    const int oy0 = gy * 2;                                       // conv rows oy0, oy0+1
    const int tid = threadIdx.x;
    const int wid = tid >> 6, lane = tid & 63;
    const int l15 = lane & 15, kl8 = (lane >> 4) << 3;
    const int g16 = gn * 4 + wid;
    const int co = g16 * 16 + l15;

    const ushort_t* xb = y2 + (size_t)b * 32 * 32 * 128;
    const f32x4 z4 = {0.f, 0.f, 0.f, 0.f};
    f32x4 acc[2] = {z4, z4};

#pragma unroll 1
    for (int tap = 0; tap < 9; ++tap) {
        const int ky = tap >= 6 ? 2 : (tap >= 3 ? 1 : 0), kx = tap - ky * 3;
        const int iyA = 2 * oy0 - 1 + ky;
        const int c = 2 * l15 - 1 + kx;
        const bool cok = (c >= 0);
#pragma unroll
        for (int h = 0; h < 4; ++h) {
            const int ci0 = h * 32;
            const int kc = tap * 4 + h;
            bf16x8 aF[2];
#pragma unroll
            for (int mf = 0; mf < 2; ++mf) {
                const int iy = iyA + 2 * mf;
                bf16x8 r = {0, 0, 0, 0, 0, 0, 0, 0};
                if (cok && iy >= 0) r = *reinterpret_cast<const bf16x8*>(xb + ((size_t)iy * 32 + c) * 128 + ci0 + kl8);
                aF[mf] = r;
            }
            const bf16x8 bF = *reinterpret_cast<const bf16x8*>(wpk3 + ((size_t)(kc * 16 + g16) * 64 + lane) * 8);
#pragma unroll
            for (int mf = 0; mf < 2; ++mf)
                acc[mf] = __builtin_amdgcn_mfma_f32_16x16x32_bf16(aF[mf], bF, acc[mf], 0, 0, 0);
        }
    }
    const int kg = lane >> 4;
    const float bias = b3[co];
#pragma unroll
    for (int p = 0; p < 2; ++p) {
        float v = fmaxf(fmaxf(acc[0][2 * p], acc[0][2 * p + 1]),
                        fmaxf(acc[1][2 * p], acc[1][2 * p + 1]));
        const int px = kg * 2 + p;
        y3[((size_t)(b * 8 + gy) * 8 + px) * 256 + co] = f2b(fmaxf(v + bias, 0.f));
    }
}

// ---------------- conv4 GEMM + relu + mean, fused im2col gather from y3 (K-split 4 waves)
__global__ __launch_bounds__(256) void k_conv4g(const ushort_t* __restrict__ y3,
                                                const ushort_t* __restrict__ wpk4m,
                                                const float* __restrict__ b4,
                                                float* __restrict__ feats) {
    const int g16 = blockIdx.x, b = blockIdx.y;
    const int tid = threadIdx.x, wid = tid >> 6, lane = tid & 63;
    const int l15 = lane & 15, kg = lane >> 4, kl8 = kg << 3;
    const int oy = l15 >> 2, ox = l15 & 3;
    const f32x4 z4 = {0.f, 0.f, 0.f, 0.f};
    f32x4 acc = z4;
    const ushort_t* yb = y3 + (size_t)b * 16384;
    const int kc0 = wid * 18;

#pragma unroll 3
    for (int i = 0; i < 18; ++i) {
        const int kc = kc0 + i;
        const int k0 = kc * 32 + kl8;
        const int tap = k0 >> 8, ci0 = k0 & 255;
        const int ky = tap / 3, kx = tap - 3 * (tap / 3);
        const int iy = 2 * oy - 1 + ky, ix = 2 * ox - 1 + kx;
        bf16x8 aF = {0, 0, 0, 0, 0, 0, 0, 0};
        if (iy >= 0 && ix >= 0)
            aF = *reinterpret_cast<const bf16x8*>(yb + ((iy * 8 + ix) << 8) + ci0);
        const bf16x8 bF = *reinterpret_cast<const bf16x8*>(wpk4m + ((size_t)(kc * 32 + g16) * 64 + lane) * 8);
        acc = __builtin_amdgcn_mfma_f32_16x16x32_bf16(aF, bF, acc, 0, 0, 0);
    }

    __shared__ f32x4 red[4][64];
    red[wid][lane] = acc;
    __syncthreads();
    if (wid == 0) {
        f32x4 t = red[0][lane];
        t = t + red[1][lane];
        t = t + red[2][lane];
        t = t + red[3][lane];
        const int co = g16 * 16 + l15;
        const float bias = b4[co];
        float s = fmaxf(t[0] + bias, 0.f) + fmaxf(t[1] + bias, 0.f)
                + fmaxf(t[2] + bias, 0.f) + fmaxf(t[3] + bias, 0.f);
        s += __shfl_xor(s, 16, 64);
        s += __shfl_xor(s, 32, 64);
        if (kg == 0) feats[b * 512 + co] = s * 0.0625f;
    }
}

// ---------------- head (parallel logits + split writes, bf16 vlad): grid (b=16, slice=8)
__global__ __launch_bounds__(256) void k_head(const float* __restrict__ feats,
                                              const float* __restrict__ wv,
                                              const float* __restrict__ bv,
                                              const float* __restrict__ centroids,
                                              ushort_t* __restrict__ v) {
    const int b = blockIdx.x, sl8 = blockIdx.y;
    __shared__ float sf[512];
    __shared__ float plog[4][64];
    __shared__ float sl[64];
    __shared__ float sa[64];
    for (int i = threadIdx.x; i < 512; i += 256) sf[i] = feats[b * 512 + i];
    __syncthreads();
    {
        const int k = threadIdx.x & 63, q = threadIdx.x >> 6;   // c-quarter
        float s = 0.f;
        const int c0 = q * 128;
        for (int c = c0; c < c0 + 128; ++c) s += sf[c] * wv[(size_t)k * 512 + c];
        plog[q][k] = s;
    }
    __syncthreads();
    if (threadIdx.x < 64) {
        const int k = threadIdx.x;
        sl[k] = plog[0][k] + plog[1][k] + plog[2][k] + plog[3][k] + bv[k];
    }
    __syncthreads();
    if (threadIdx.x < 64) {
        const int k = threadIdx.x;
        float m = -1e30f;
        for (int i = 0; i < 64; ++i) m = fmaxf(m, sl[i]);
        float sum = 0.f;
        for (int i = 0; i < 64; ++i) sum += __expf(sl[i] - m);
        sa[k] = __expf(sl[k] - m) / sum;
    }
    __syncthreads();
    const int i4end = (sl8 + 1) * 4096;
    for (int i4 = sl8 * 4096 + threadIdx.x * 4; i4 < i4end; i4 += 1024) {
        const int k = i4 >> 9;
        const float a_ = sa[k];
        const float4 c4 = *(const float4*)(centroids + i4);
        const float4 f4 = *(const float4*)(&sf[i4 & 511]);
        union { ushort_t u[4]; uint2 w; } pk;
        pk.u[0] = f2b(a_ * (f4.x - c4.x));
        pk.u[1] = f2b(a_ * (f4.y - c4.y));
        pk.u[2] = f2b(a_ * (f4.z - c4.z));
        pk.u[3] = f2b(a_ * (f4.w - c4.w));
        *(uint2*)(v + (size_t)b * 32768 + i4) = pk.w;
    }
}

// ---------------- fc1 MFMA: part = v_bf16[16 x 32768] @ fw1^T, K-split (R22 config)
// grid (g16=16, by=64); A direct bf16 load, B inline fp32->bf16 cvt; 4-wave LDS reduce
__global__ __launch_bounds__(256) void k_fc1m(const ushort_t* __restrict__ v,
                                              const float* __restrict__ fw1,
                                              float* __restrict__ part) {
    const int g16 = blockIdx.x, by = blockIdx.y;
    const int tid = threadIdx.x, wid = tid >> 6, lane = tid & 63;
    const int l15 = lane & 15, kg = lane >> 4;
    const f32x4 z4 = {0.f, 0.f, 0.f, 0.f};
    f32x4 acc = z4;
    const ushort_t* vrow = v + (size_t)l15 * 32768;                // batch = l15
    const float* wrow = fw1 + (size_t)(g16 * 16 + l15) * 32768;    // d = g16*16+l15
    const int kc0 = by * 16 + wid * 4;

#pragma unroll
    for (int i = 0; i < 4; ++i) {
        const int j0 = (kc0 + i) * 32 + kg * 8;
        const bf16x8 aF = *reinterpret_cast<const bf16x8*>(vrow + j0);
        const float4 wa = *(const float4*)(wrow + j0);
        const float4 wb = *(const float4*)(wrow + j0 + 4);
        bf16x8 bF;
        bF[0] = (short)f2b(wa.x); bF[1] = (short)f2b(wa.y);
        bF[2] = (short)f2b(wa.z); bF[3] = (short)f2b(wa.w);
        bF[4] = (short)f2b(wb.x); bF[5] = (short)f2b(wb.y);
        bF[6] = (short)f2b(wb.z); bF[7] = (short)f2b(wb.w);
        acc = __builtin_amdgcn_mfma_f32_16x16x32_bf16(aF, bF, acc, 0, 0, 0);
    }

    __shared__ f32x4 red[4][64];
    red[wid][lane] = acc;
    __syncthreads();
    if (wid == 0) {
        f32x4 t = red[0][lane];
        t = t + red[1][lane];
        t = t + red[2][lane];
        t = t + red[3][lane];
#pragma unroll
        for (int r = 0; r < 4; ++r)
            part[((size_t)by * 16 + (kg * 4 + r)) * 256 + g16 * 16 + l15] = t[r];
    }
}

// ---------------- fc2 (+fc1 reduce/bias/relu) + L2 norm; 64 K-partials, 1024 threads
__global__ __launch_bounds__(1024) void k_fc2(const float* __restrict__ part,
                                              const float* __restrict__ fb1,
                                              const float* __restrict__ fw2,
                                              const float* __restrict__ fb2,
                                              float* __restrict__ out) {
    const int b = blockIdx.x;
    const int tid = threadIdx.x;
    const int dd = tid & 255, jq = tid >> 8;              // 4 quarters
    __shared__ float sd[256];
    __shared__ float pr[4][256];
    __shared__ float sq[256];
    // fc1 reduce: 64 ks split across jq (16 each)
    float t = 0.f;
    const int ks0 = jq * 16;
    for (int ks = ks0; ks < ks0 + 16; ++ks) t += part[((size_t)ks * 16 + b) * 256 + dd];
    pr[jq][dd] = t;
    __syncthreads();
    if (jq == 0)
        sd[dd] = fmaxf(pr[0][dd] + pr[1][dd] + pr[2][dd] + pr[3][dd] + fb1[dd], 0.f);
    __syncthreads();
    // fc2: j-range split across jq
    float s = 0.f;
    const int j0 = jq * 64;
    for (int j = j0; j < j0 + 64; ++j) s += sd[j] * fw2[(size_t)dd * 256 + j];
    pr[jq][dd] = s;
    __syncthreads();
    float sfull = 0.f;
    if (jq == 0) {
        sfull = pr[0][dd] + pr[1][dd] + pr[2][dd] + pr[3][dd] + fb2[dd];
        sq[dd] = sfull * sfull;
    }
    __syncthreads();
    for (int off = 128; off >= 1; off >>= 1) {
        if (jq == 0 && dd < off) sq[dd] += sq[dd + off];
        __syncthreads();
    }
    if (jq == 0) out[b * 256 + dd] = sfull * rsqrtf(sq[0]);
}

extern "C" void kernel_launch(void* const* d_in, const int* in_sizes, int n_in,
                              void* d_out, int out_size, void* d_ws, size_t ws_size,
                              hipStream_t stream) {
    const float* x    = (const float*)d_in[0];
    const float* w1   = (const float*)d_in[1];
    const float* b1   = (const float*)d_in[2];
    const float* w2   = (const float*)d_in[3];
    const float* b2   = (const float*)d_in[4];
    const float* w3   = (const float*)d_in[5];
    const float* b3   = (const float*)d_in[6];
    const float* w4   = (const float*)d_in[7];
    const float* b4   = (const float*)d_in[8];
    const float* wv   = (const float*)d_in[9];
    const float* bv   = (const float*)d_in[10];
    const float* cen  = (const float*)d_in[11];
    const float* fw1  = (const float*)d_in[12];
    const float* fb1  = (const float*)d_in[13];
    const float* fw2  = (const float*)d_in[14];
    const float* fb2  = (const float*)d_in[15];
    float* out = (float*)d_out;

    char* p = (char*)d_ws;
    ushort_t* y1    = (ushort_t*)p; p += 33554432;  // 16*128*128*64 bf16
    ushort_t* wpk2  = (ushort_t*)p; p += 147456;    // 73728 bf16
    ushort_t* wpk3  = (ushort_t*)p; p += 589824;    // 294912 bf16
    ushort_t* wpk4m = (ushort_t*)p; p += 2359296;   // 1179648 bf16
    ushort_t* wpk1  = (ushort_t*)p; p += 4096;      // 2048 bf16
    ushort_t* y2    = (ushort_t*)p; p += 4194304;   // 16*32*32*128 bf16
    ushort_t* y3    = (ushort_t*)p; p += 524288;    // 16*8*8*256 bf16
    float*    feats = (float*)p;    p += 32768;     // 16*512
    ushort_t* vbuf  = (ushort_t*)p; p += 1048576;   // 16*32768 bf16
    float*    part  = (float*)p;    p += 1048576;   // 64*16*256 f32

    k_packall<<<693, 256, 0, stream>>>(w1, w2, w3, w4, wpk1, wpk2, wpk3, wpk4m);
    k_conv1f<<<dim3(64, 2, 16), 256, 0, stream>>>(x, wpk1, b1, y1);
    k_conv2s<<<dim3(32, 4, 16), 256, 0, stream>>>(y1, wpk2, b2, y2);
    k_conv3m<<<dim3(8, 4, 16), 256, 0, stream>>>(y2, wpk3, b3, y3);
    k_conv4g<<<dim3(32, 16), 256, 0, stream>>>(y3, wpk4m, b4, feats);
    k_head<<<dim3(16, 8), 256, 0, stream>>>(feats, wv, bv, cen, vbuf);
    k_fc1m<<<dim3(16, 64), 256, 0, stream>>>(vbuf, fw1, part);
    k_fc2<<<16, 1024, 0, stream>>>(part, fb1, fw2, fb2, out);
}